// Round 4
// baseline (360.312 us; speedup 1.0000x reference)
//
#include <hip/hip_runtime.h>

// Problem constants (from reference):
//   D = 262144 slots, d = 128, KH = 32 slots/key, B = 32768 keys
#define D_SLOTS   262144
#define D_FEAT    128
#define KH_SLOTS  32
#define B_KEYS    32768
#define NPAIR     (B_KEYS * KH_SLOTS)      // 1,048,576 (b,slot) pairs
#define SCALE_F   0.17677669529663687f     // 1/sqrt(32)
#define EPS_F     1e-8f

// Strategy (R14 = R12 revert + TIMING PROBE): vb back to bf16 (R13's fp8-vb
// FAILED accuracy: 1.37e-2 > 5.08e-3 threshold; bf16 config passes at
// 4.88e-3 -> only 4% headroom, dbg-fp8 consumes the budget. NO further
// quantization anywhere.)
// PROBE: k4 and k5 are idempotent -> launch each TWICE. Output identical;
// dur_us = baseline + (t_k4 + t_k5). Pre-committed read:
//   delta > 100us -> gathers dominate -> attack gather bytes/fusion
//   delta < 60us  -> front-end (memset/atomics/scan/fill/launches) dominates
// If t_k4 or t_k5 >= 78us the duplicate surfaces in top-5 with counters.
//
// d_in[2] ("memory", 134 MB, restored each launch) reused as scratch:
//   dbg  uint2[D*16]   @ 0            debiased fp8 rows, 128 B/row (33.5 MB)
//   vb   uint[B*64]    @ D*32         values as bf16 (8.4 MB)
//   rank uchar[NPAIR]  @ D*32+B*64    in-bucket rank per pair (1 MB)
// ws (ints): hist[D], offs[D], bsum[256], sorted ushort[NPAIR]  (~4.2 MB)

typedef float floatx2 __attribute__((ext_vector_type(2)));
typedef float floatx4 __attribute__((ext_vector_type(4)));

__device__ __forceinline__ unsigned pack_bf16x2(float a, float b) {
    unsigned ua = __float_as_uint(a), ub = __float_as_uint(b);
    ua = (ua + 0x7FFFu + ((ua >> 16) & 1u)) >> 16;
    ub = (ub + 0x7FFFu + ((ub >> 16) & 1u)) >> 16;
    return ua | (ub << 16);
}

#define ACC8(acc, m)                                   \
    acc[0] += __uint_as_float((m).x << 16);            \
    acc[1] += __uint_as_float((m).x & 0xFFFF0000u);    \
    acc[2] += __uint_as_float((m).y << 16);            \
    acc[3] += __uint_as_float((m).y & 0xFFFF0000u);    \
    acc[4] += __uint_as_float((m).z << 16);            \
    acc[5] += __uint_as_float((m).z & 0xFFFF0000u);    \
    acc[6] += __uint_as_float((m).w << 16);            \
    acc[7] += __uint_as_float((m).w & 0xFFFF0000u);

// ---- fused: values -> bf16 (one float4/thread) + histogram + rank ----
__global__ __launch_bounds__(256) void k_cvt_hist(const float4* __restrict__ v4,
                                                  const int* __restrict__ indices,
                                                  uint2* __restrict__ vb2,
                                                  int* __restrict__ hist,
                                                  unsigned char* __restrict__ rank) {
    const int p = blockIdx.x * 256 + threadIdx.x;
    const int idx = indices[p];
    const float4 a = v4[p];
    vb2[p] = make_uint2(pack_bf16x2(a.x, a.y), pack_bf16x2(a.z, a.w));
    rank[p] = (unsigned char)atomicAdd(&hist[idx], 1);
}

// ---- scan step a: per-block (1024-elem) sums ----
__global__ __launch_bounds__(256) void k2a_blocksum(const int* __restrict__ hist,
                                                    int* __restrict__ bsum) {
    __shared__ int red[256];
    const int t = threadIdx.x;
    const int base = blockIdx.x * 1024;
    int s = hist[base + t] + hist[base + t + 256] +
            hist[base + t + 512] + hist[base + t + 768];
    red[t] = s;
    __syncthreads();
    for (int off = 128; off > 0; off >>= 1) {
        if (t < off) red[t] += red[t + off];
        __syncthreads();
    }
    if (t == 0) bsum[blockIdx.x] = red[0];
}

// ---- scan step b+c fused ----
__global__ __launch_bounds__(256) void k2c_scan(const int* __restrict__ hist,
                                                const int* __restrict__ bsum,
                                                int* __restrict__ offs) {
    __shared__ int btmp[256];
    __shared__ int tmp[256];
    const int t = threadIdx.x;
    btmp[t] = bsum[t];
    __syncthreads();
    for (int off = 1; off < 256; off <<= 1) {  // inclusive scan of block sums
        int x = (t >= off) ? btmp[t - off] : 0;
        __syncthreads();
        btmp[t] += x;
        __syncthreads();
    }
    const int base_excl = btmp[blockIdx.x] - bsum[blockIdx.x];

    const int base = blockIdx.x * 1024 + t * 4;
    const int h0 = hist[base], h1 = hist[base + 1], h2 = hist[base + 2], h3 = hist[base + 3];
    const int tot = h0 + h1 + h2 + h3;
    tmp[t] = tot;
    __syncthreads();
    for (int off = 1; off < 256; off <<= 1) {
        int x = (t >= off) ? tmp[t - off] : 0;
        __syncthreads();
        tmp[t] += x;
        __syncthreads();
    }
    const int o0 = base_excl + (tmp[t] - tot);
    ((int4*)offs)[base >> 2] = make_int4(o0, o0 + h0, o0 + h0 + h1, o0 + h0 + h1 + h2);
}

// ---- bucket fill, atomic-free ----
__global__ __launch_bounds__(256) void k3_fill(const int* __restrict__ indices,
                                               const int* __restrict__ offs,
                                               const unsigned char* __restrict__ rank,
                                               unsigned short* __restrict__ sorted) {
    const int p = blockIdx.x * 256 + threadIdx.x;
    const int idx = indices[p];
    sorted[offs[idx] + (int)rank[p]] = (unsigned short)(p >> 5);
}

// ---- segmented reduce + fused debias (bf16 in, FP8 E4M3 out), 4-way MLP ----
__global__ __launch_bounds__(256) void k4_accum(const int* __restrict__ hist,
                                                const int* __restrict__ offs,
                                                const unsigned short* __restrict__ sorted,
                                                const uint4* __restrict__ vb,
                                                uint2* __restrict__ dbg) {
    const int t = threadIdx.x;
    const int sub = t >> 4;
    const int lane = t & 15;
    const int slot = blockIdx.x * 16 + sub;
    const int n = hist[slot];
    if (n == 0) return;  // untouched slot: never gathered
    const int off = offs[slot];
    float acc[8] = {0.f, 0.f, 0.f, 0.f, 0.f, 0.f, 0.f, 0.f};
    int j = 0;
    for (; j + 4 <= n; j += 4) {
        const int s0 = sorted[off + j + 0];
        const int s1 = sorted[off + j + 1];
        const int s2 = sorted[off + j + 2];
        const int s3 = sorted[off + j + 3];
        const uint4 m0 = vb[(size_t)s0 * 16 + lane];
        const uint4 m1 = vb[(size_t)s1 * 16 + lane];
        const uint4 m2 = vb[(size_t)s2 * 16 + lane];
        const uint4 m3 = vb[(size_t)s3 * 16 + lane];
        ACC8(acc, m0); ACC8(acc, m1); ACC8(acc, m2); ACC8(acc, m3);
    }
    for (; j < n; ++j) {
        const int src = sorted[off + j];
        const uint4 m = vb[(size_t)src * 16 + lane];
        ACC8(acc, m);
    }
    const float g = SCALE_F / ((float)n + EPS_F);
    int lo = __builtin_amdgcn_cvt_pk_fp8_f32(acc[0] * g, acc[1] * g, 0, false);
    lo     = __builtin_amdgcn_cvt_pk_fp8_f32(acc[2] * g, acc[3] * g, lo, true);
    int hi = __builtin_amdgcn_cvt_pk_fp8_f32(acc[4] * g, acc[5] * g, 0, false);
    hi     = __builtin_amdgcn_cvt_pk_fp8_f32(acc[6] * g, acc[7] * g, hi, true);
    dbg[(size_t)slot * 16 + lane] = make_uint2((unsigned)lo, (unsigned)hi);
}

// ---- gather: out[b] = mean over 32 pre-debiased fp8 rows ----
// 16 threads per key (8 row-lanes x 2 slot-halves), 16 keys/block.
__global__ __launch_bounds__(256) void k5_gather(const int* __restrict__ indices,
                                                 const uint4* __restrict__ dbg,
                                                 float* __restrict__ out) {
    __shared__ int sidx[16 * KH_SLOTS];
    const int t = threadIdx.x;
    const int* ibase = indices + (size_t)blockIdx.x * 16 * KH_SLOTS;
    sidx[t]       = ibase[t];
    sidx[t + 256] = ibase[t + 256];
    __syncthreads();

    const int sub  = t >> 4;        // key within block (0..15)
    const int lane = t & 7;         // uint4 index within the 128-B fp8 row
    const int half = (t >> 3) & 1;  // which 16 of the 32 slots
    const int b = blockIdx.x * 16 + sub;

    float acc[16];
    #pragma unroll
    for (int i = 0; i < 16; ++i) acc[i] = 0.f;

    const int* irow = sidx + sub * KH_SLOTS + half * 16;
    #pragma unroll
    for (int s = 0; s < 16; ++s) {
        const int idx = irow[s];
        const uint4 w = dbg[(size_t)idx * 8 + lane];
        const floatx2 p0 = __builtin_amdgcn_cvt_pk_f32_fp8((int)w.x, false);
        const floatx2 p1 = __builtin_amdgcn_cvt_pk_f32_fp8((int)w.x, true);
        const floatx2 p2 = __builtin_amdgcn_cvt_pk_f32_fp8((int)w.y, false);
        const floatx2 p3 = __builtin_amdgcn_cvt_pk_f32_fp8((int)w.y, true);
        const floatx2 p4 = __builtin_amdgcn_cvt_pk_f32_fp8((int)w.z, false);
        const floatx2 p5 = __builtin_amdgcn_cvt_pk_f32_fp8((int)w.z, true);
        const floatx2 p6 = __builtin_amdgcn_cvt_pk_f32_fp8((int)w.w, false);
        const floatx2 p7 = __builtin_amdgcn_cvt_pk_f32_fp8((int)w.w, true);
        acc[0]  += p0.x; acc[1]  += p0.y; acc[2]  += p1.x; acc[3]  += p1.y;
        acc[4]  += p2.x; acc[5]  += p2.y; acc[6]  += p3.x; acc[7]  += p3.y;
        acc[8]  += p4.x; acc[9]  += p4.y; acc[10] += p5.x; acc[11] += p5.y;
        acc[12] += p6.x; acc[13] += p6.y; acc[14] += p7.x; acc[15] += p7.y;
    }

    // merge the two slot-halves: partner differs only in bit 3 of tid
    #pragma unroll
    for (int i = 0; i < 16; ++i) acc[i] += __shfl_xor(acc[i], 8);

    const float inv = 1.0f / (float)KH_SLOTS;
    const int o = half * 8;  // half 0 writes floats 0..7, half 1 writes 8..15
    floatx4* orow = (floatx4*)(out + (size_t)b * D_FEAT + lane * 16);
    floatx4 w0 = {acc[o + 0] * inv, acc[o + 1] * inv, acc[o + 2] * inv, acc[o + 3] * inv};
    floatx4 w1 = {acc[o + 4] * inv, acc[o + 5] * inv, acc[o + 6] * inv, acc[o + 7] * inv};
    __builtin_nontemporal_store(w0, orow + half * 2 + 0);
    __builtin_nontemporal_store(w1, orow + half * 2 + 1);
}

extern "C" void kernel_launch(void* const* d_in, const int* in_sizes, int n_in,
                              void* d_out, int out_size, void* d_ws, size_t ws_size,
                              hipStream_t stream) {
    const int*   indices = (const int*)d_in[0];
    const float* values  = (const float*)d_in[1];
    unsigned*    mem_u   = (unsigned*)d_in[2];   // reused as scratch
    float*       out     = (float*)d_out;

    uint2*         dbg  = (uint2*)mem_u;                             // [D*16] uint2
    unsigned*      vb   = mem_u + (size_t)D_SLOTS * 32;              // [B*64] uints
    unsigned char* rank = (unsigned char*)(mem_u + (size_t)D_SLOTS * 32 + (size_t)B_KEYS * 64);

    int* wsi    = (int*)d_ws;
    int* hist   = wsi;
    int* offs   = wsi + D_SLOTS;
    int* bsum   = wsi + 2 * D_SLOTS;
    unsigned short* sorted = (unsigned short*)(wsi + 2 * D_SLOTS + 256);

    (void)hipMemsetAsync(hist, 0, (size_t)D_SLOTS * sizeof(int), stream);
    k_cvt_hist  <<<NPAIR / 256, 256, 0, stream>>>((const float4*)values, indices,
                                                  (uint2*)vb, hist, rank);
    k2a_blocksum<<<256, 256, 0, stream>>>(hist, bsum);
    k2c_scan    <<<256, 256, 0, stream>>>(hist, bsum, offs);
    k3_fill     <<<NPAIR / 256, 256, 0, stream>>>(indices, offs, rank, sorted);
    // --- PROBE: k4/k5 are idempotent; run each twice. Output identical,
    //     dur_us gains exactly t_k4 + t_k5 (second-run, warm-cache). ---
    k4_accum    <<<D_SLOTS / 16, 256, 0, stream>>>(hist, offs, sorted, (const uint4*)vb, dbg);
    k4_accum    <<<D_SLOTS / 16, 256, 0, stream>>>(hist, offs, sorted, (const uint4*)vb, dbg);
    k5_gather   <<<B_KEYS / 16, 256, 0, stream>>>(indices, (const uint4*)dbg, out);
    k5_gather   <<<B_KEYS / 16, 256, 0, stream>>>(indices, (const uint4*)dbg, out);
}

// Round 6
// 340.328 us; speedup vs baseline: 1.0587x; 1.0587x over previous
//
#include <hip/hip_runtime.h>

// Problem constants (from reference):
//   D = 262144 slots, d = 128, KH = 32 slots/key, B = 32768 keys
#define D_SLOTS   262144
#define D_FEAT    128
#define KH_SLOTS  32
#define B_KEYS    32768
#define NPAIR     (B_KEYS * KH_SLOTS)      // 1,048,576 (b,slot) pairs
#define SCALE_F   0.17677669529663687f     // 1/sqrt(32)
#define EPS_F     1e-8f

// Strategy (R16 = R15 resubmit; container infra failed last round):
// R14 established t(k4+k5) ~= 65us warm -> ~230us lives in
// {memset,k1,k2a,k2c,k3}+node overhead. This round splits that:
// duplicate (memset; k1). Rebuilding hist from zero is order-independent
// and rank re-assignment is any-valid-permutation, so output is
// bit-compatible; dur gains exactly t(memset+k1).
// Pre-committed: >=100us -> k1 atomics dominate; <=40us -> sort3/overhead
// dominates -> linked-list redesign next.
//
// d_in[2] ("memory", 134 MB, restored each launch) reused as scratch:
//   dbg  uint2[D*16]   @ 0            debiased fp8 rows, 128 B/row (33.5 MB)
//   vb   uint[B*64]    @ D*32         values as bf16 (8.4 MB)
//   rank uchar[NPAIR]  @ D*32+B*64    in-bucket rank per pair (1 MB)
// ws (ints): hist[D], offs[D], bsum[256], sorted ushort[NPAIR]  (~4.2 MB)

typedef float floatx2 __attribute__((ext_vector_type(2)));
typedef float floatx4 __attribute__((ext_vector_type(4)));

__device__ __forceinline__ unsigned pack_bf16x2(float a, float b) {
    unsigned ua = __float_as_uint(a), ub = __float_as_uint(b);
    ua = (ua + 0x7FFFu + ((ua >> 16) & 1u)) >> 16;
    ub = (ub + 0x7FFFu + ((ub >> 16) & 1u)) >> 16;
    return ua | (ub << 16);
}

#define ACC8(acc, m)                                   \
    acc[0] += __uint_as_float((m).x << 16);            \
    acc[1] += __uint_as_float((m).x & 0xFFFF0000u);    \
    acc[2] += __uint_as_float((m).y << 16);            \
    acc[3] += __uint_as_float((m).y & 0xFFFF0000u);    \
    acc[4] += __uint_as_float((m).z << 16);            \
    acc[5] += __uint_as_float((m).z & 0xFFFF0000u);    \
    acc[6] += __uint_as_float((m).w << 16);            \
    acc[7] += __uint_as_float((m).w & 0xFFFF0000u);

// ---- fused: values -> bf16 (one float4/thread) + histogram + rank ----
__global__ __launch_bounds__(256) void k_cvt_hist(const float4* __restrict__ v4,
                                                  const int* __restrict__ indices,
                                                  uint2* __restrict__ vb2,
                                                  int* __restrict__ hist,
                                                  unsigned char* __restrict__ rank) {
    const int p = blockIdx.x * 256 + threadIdx.x;
    const int idx = indices[p];
    const float4 a = v4[p];
    vb2[p] = make_uint2(pack_bf16x2(a.x, a.y), pack_bf16x2(a.z, a.w));
    rank[p] = (unsigned char)atomicAdd(&hist[idx], 1);
}

// ---- scan step a: per-block (1024-elem) sums ----
__global__ __launch_bounds__(256) void k2a_blocksum(const int* __restrict__ hist,
                                                    int* __restrict__ bsum) {
    __shared__ int red[256];
    const int t = threadIdx.x;
    const int base = blockIdx.x * 1024;
    int s = hist[base + t] + hist[base + t + 256] +
            hist[base + t + 512] + hist[base + t + 768];
    red[t] = s;
    __syncthreads();
    for (int off = 128; off > 0; off >>= 1) {
        if (t < off) red[t] += red[t + off];
        __syncthreads();
    }
    if (t == 0) bsum[blockIdx.x] = red[0];
}

// ---- scan step b+c fused ----
__global__ __launch_bounds__(256) void k2c_scan(const int* __restrict__ hist,
                                                const int* __restrict__ bsum,
                                                int* __restrict__ offs) {
    __shared__ int btmp[256];
    __shared__ int tmp[256];
    const int t = threadIdx.x;
    btmp[t] = bsum[t];
    __syncthreads();
    for (int off = 1; off < 256; off <<= 1) {  // inclusive scan of block sums
        int x = (t >= off) ? btmp[t - off] : 0;
        __syncthreads();
        btmp[t] += x;
        __syncthreads();
    }
    const int base_excl = btmp[blockIdx.x] - bsum[blockIdx.x];

    const int base = blockIdx.x * 1024 + t * 4;
    const int h0 = hist[base], h1 = hist[base + 1], h2 = hist[base + 2], h3 = hist[base + 3];
    const int tot = h0 + h1 + h2 + h3;
    tmp[t] = tot;
    __syncthreads();
    for (int off = 1; off < 256; off <<= 1) {
        int x = (t >= off) ? tmp[t - off] : 0;
        __syncthreads();
        tmp[t] += x;
        __syncthreads();
    }
    const int o0 = base_excl + (tmp[t] - tot);
    ((int4*)offs)[base >> 2] = make_int4(o0, o0 + h0, o0 + h0 + h1, o0 + h0 + h1 + h2);
}

// ---- bucket fill, atomic-free ----
__global__ __launch_bounds__(256) void k3_fill(const int* __restrict__ indices,
                                               const int* __restrict__ offs,
                                               const unsigned char* __restrict__ rank,
                                               unsigned short* __restrict__ sorted) {
    const int p = blockIdx.x * 256 + threadIdx.x;
    const int idx = indices[p];
    sorted[offs[idx] + (int)rank[p]] = (unsigned short)(p >> 5);
}

// ---- segmented reduce + fused debias (bf16 in, FP8 E4M3 out), 4-way MLP ----
__global__ __launch_bounds__(256) void k4_accum(const int* __restrict__ hist,
                                                const int* __restrict__ offs,
                                                const unsigned short* __restrict__ sorted,
                                                const uint4* __restrict__ vb,
                                                uint2* __restrict__ dbg) {
    const int t = threadIdx.x;
    const int sub = t >> 4;
    const int lane = t & 15;
    const int slot = blockIdx.x * 16 + sub;
    const int n = hist[slot];
    if (n == 0) return;  // untouched slot: never gathered
    const int off = offs[slot];
    float acc[8] = {0.f, 0.f, 0.f, 0.f, 0.f, 0.f, 0.f, 0.f};
    int j = 0;
    for (; j + 4 <= n; j += 4) {
        const int s0 = sorted[off + j + 0];
        const int s1 = sorted[off + j + 1];
        const int s2 = sorted[off + j + 2];
        const int s3 = sorted[off + j + 3];
        const uint4 m0 = vb[(size_t)s0 * 16 + lane];
        const uint4 m1 = vb[(size_t)s1 * 16 + lane];
        const uint4 m2 = vb[(size_t)s2 * 16 + lane];
        const uint4 m3 = vb[(size_t)s3 * 16 + lane];
        ACC8(acc, m0); ACC8(acc, m1); ACC8(acc, m2); ACC8(acc, m3);
    }
    for (; j < n; ++j) {
        const int src = sorted[off + j];
        const uint4 m = vb[(size_t)src * 16 + lane];
        ACC8(acc, m);
    }
    const float g = SCALE_F / ((float)n + EPS_F);
    int lo = __builtin_amdgcn_cvt_pk_fp8_f32(acc[0] * g, acc[1] * g, 0, false);
    lo     = __builtin_amdgcn_cvt_pk_fp8_f32(acc[2] * g, acc[3] * g, lo, true);
    int hi = __builtin_amdgcn_cvt_pk_fp8_f32(acc[4] * g, acc[5] * g, 0, false);
    hi     = __builtin_amdgcn_cvt_pk_fp8_f32(acc[6] * g, acc[7] * g, hi, true);
    dbg[(size_t)slot * 16 + lane] = make_uint2((unsigned)lo, (unsigned)hi);
}

// ---- gather: out[b] = mean over 32 pre-debiased fp8 rows ----
// 16 threads per key (8 row-lanes x 2 slot-halves), 16 keys/block.
__global__ __launch_bounds__(256) void k5_gather(const int* __restrict__ indices,
                                                 const uint4* __restrict__ dbg,
                                                 float* __restrict__ out) {
    __shared__ int sidx[16 * KH_SLOTS];
    const int t = threadIdx.x;
    const int* ibase = indices + (size_t)blockIdx.x * 16 * KH_SLOTS;
    sidx[t]       = ibase[t];
    sidx[t + 256] = ibase[t + 256];
    __syncthreads();

    const int sub  = t >> 4;        // key within block (0..15)
    const int lane = t & 7;         // uint4 index within the 128-B fp8 row
    const int half = (t >> 3) & 1;  // which 16 of the 32 slots
    const int b = blockIdx.x * 16 + sub;

    float acc[16];
    #pragma unroll
    for (int i = 0; i < 16; ++i) acc[i] = 0.f;

    const int* irow = sidx + sub * KH_SLOTS + half * 16;
    #pragma unroll
    for (int s = 0; s < 16; ++s) {
        const int idx = irow[s];
        const uint4 w = dbg[(size_t)idx * 8 + lane];
        const floatx2 p0 = __builtin_amdgcn_cvt_pk_f32_fp8((int)w.x, false);
        const floatx2 p1 = __builtin_amdgcn_cvt_pk_f32_fp8((int)w.x, true);
        const floatx2 p2 = __builtin_amdgcn_cvt_pk_f32_fp8((int)w.y, false);
        const floatx2 p3 = __builtin_amdgcn_cvt_pk_f32_fp8((int)w.y, true);
        const floatx2 p4 = __builtin_amdgcn_cvt_pk_f32_fp8((int)w.z, false);
        const floatx2 p5 = __builtin_amdgcn_cvt_pk_f32_fp8((int)w.z, true);
        const floatx2 p6 = __builtin_amdgcn_cvt_pk_f32_fp8((int)w.w, false);
        const floatx2 p7 = __builtin_amdgcn_cvt_pk_f32_fp8((int)w.w, true);
        acc[0]  += p0.x; acc[1]  += p0.y; acc[2]  += p1.x; acc[3]  += p1.y;
        acc[4]  += p2.x; acc[5]  += p2.y; acc[6]  += p3.x; acc[7]  += p3.y;
        acc[8]  += p4.x; acc[9]  += p4.y; acc[10] += p5.x; acc[11] += p5.y;
        acc[12] += p6.x; acc[13] += p6.y; acc[14] += p7.x; acc[15] += p7.y;
    }

    // merge the two slot-halves: partner differs only in bit 3 of tid
    #pragma unroll
    for (int i = 0; i < 16; ++i) acc[i] += __shfl_xor(acc[i], 8);

    const float inv = 1.0f / (float)KH_SLOTS;
    const int o = half * 8;  // half 0 writes floats 0..7, half 1 writes 8..15
    floatx4* orow = (floatx4*)(out + (size_t)b * D_FEAT + lane * 16);
    floatx4 w0 = {acc[o + 0] * inv, acc[o + 1] * inv, acc[o + 2] * inv, acc[o + 3] * inv};
    floatx4 w1 = {acc[o + 4] * inv, acc[o + 5] * inv, acc[o + 6] * inv, acc[o + 7] * inv};
    __builtin_nontemporal_store(w0, orow + half * 2 + 0);
    __builtin_nontemporal_store(w1, orow + half * 2 + 1);
}

extern "C" void kernel_launch(void* const* d_in, const int* in_sizes, int n_in,
                              void* d_out, int out_size, void* d_ws, size_t ws_size,
                              hipStream_t stream) {
    const int*   indices = (const int*)d_in[0];
    const float* values  = (const float*)d_in[1];
    unsigned*    mem_u   = (unsigned*)d_in[2];   // reused as scratch
    float*       out     = (float*)d_out;

    uint2*         dbg  = (uint2*)mem_u;                             // [D*16] uint2
    unsigned*      vb   = mem_u + (size_t)D_SLOTS * 32;              // [B*64] uints
    unsigned char* rank = (unsigned char*)(mem_u + (size_t)D_SLOTS * 32 + (size_t)B_KEYS * 64);

    int* wsi    = (int*)d_ws;
    int* hist   = wsi;
    int* offs   = wsi + D_SLOTS;
    int* bsum   = wsi + 2 * D_SLOTS;
    unsigned short* sorted = (unsigned short*)(wsi + 2 * D_SLOTS + 256);

    // --- PROBE #2: run (memset + k1) twice. hist rebuild from zero is
    //     order-independent; rank re-assignment is any-valid-permutation.
    //     Final state identical; dur gains exactly t(memset + k1). ---
    (void)hipMemsetAsync(hist, 0, (size_t)D_SLOTS * sizeof(int), stream);
    k_cvt_hist  <<<NPAIR / 256, 256, 0, stream>>>((const float4*)values, indices,
                                                  (uint2*)vb, hist, rank);
    (void)hipMemsetAsync(hist, 0, (size_t)D_SLOTS * sizeof(int), stream);
    k_cvt_hist  <<<NPAIR / 256, 256, 0, stream>>>((const float4*)values, indices,
                                                  (uint2*)vb, hist, rank);
    k2a_blocksum<<<256, 256, 0, stream>>>(hist, bsum);
    k2c_scan    <<<256, 256, 0, stream>>>(hist, bsum, offs);
    k3_fill     <<<NPAIR / 256, 256, 0, stream>>>(indices, offs, rank, sorted);
    k4_accum    <<<D_SLOTS / 16, 256, 0, stream>>>(hist, offs, sorted, (const uint4*)vb, dbg);
    k5_gather   <<<B_KEYS / 16, 256, 0, stream>>>(indices, (const uint4*)dbg, out);
}

// Round 7
// 296.255 us; speedup vs baseline: 1.2162x; 1.1488x over previous
//
#include <hip/hip_runtime.h>

// Problem constants (from reference):
//   D = 262144 slots, d = 128, KH = 32 slots/key, B = 32768 keys
#define D_SLOTS   262144
#define D_FEAT    128
#define KH_SLOTS  32
#define B_KEYS    32768
#define NPAIR     (B_KEYS * KH_SLOTS)      // 1,048,576 (b,slot) pairs
#define SCALE_F   0.17677669529663687f     // 1/sqrt(32)
#define EPS_F     1e-8f

// Strategy (R17): probes removed. Accounting from R14/R16:
//   memset+k1 ~= 45us, k4+k5 ~= 65us, sort3 ~= 20us (model) => ~135us work
//   vs 295us measured -> ~160us unaccounted. Hypothesis: the harness's
//   512 MiB re-poison fills (78us each) run INSIDE the timed window because
//   we dirty d_in[2] (scratch). 2x78 + 135 ~= 291 ~= 295.
// Change: move ALL scratch (dbg/vb/rank) into d_ws (total need ~47.2 MB),
// leaving every d_in buffer untouched. Runtime check on ws_size with exact
// R12 fallback (scratch in d_in[2]) if ws is too small -> zero-risk.
// Pre-committed: drop >=50us -> in-window restore confirmed;
// unchanged -> dispatch overhead -> merge kernels next round.
//
// ws layout (when ws_size >= ~47.2 MB):
//   hist[D] offs[D] bsum[256] sorted[NPAIR]   (4.2 MB, as before)
//   dbg  uint2[D*16]    debiased fp8 rows, 128 B/row (33.5 MB)
//   vb   uint[B*64]     values as bf16 (8.4 MB)
//   rank uchar[NPAIR]   in-bucket rank per pair (1 MB)

typedef float floatx2 __attribute__((ext_vector_type(2)));
typedef float floatx4 __attribute__((ext_vector_type(4)));

__device__ __forceinline__ unsigned pack_bf16x2(float a, float b) {
    unsigned ua = __float_as_uint(a), ub = __float_as_uint(b);
    ua = (ua + 0x7FFFu + ((ua >> 16) & 1u)) >> 16;
    ub = (ub + 0x7FFFu + ((ub >> 16) & 1u)) >> 16;
    return ua | (ub << 16);
}

#define ACC8(acc, m)                                   \
    acc[0] += __uint_as_float((m).x << 16);            \
    acc[1] += __uint_as_float((m).x & 0xFFFF0000u);    \
    acc[2] += __uint_as_float((m).y << 16);            \
    acc[3] += __uint_as_float((m).y & 0xFFFF0000u);    \
    acc[4] += __uint_as_float((m).z << 16);            \
    acc[5] += __uint_as_float((m).z & 0xFFFF0000u);    \
    acc[6] += __uint_as_float((m).w << 16);            \
    acc[7] += __uint_as_float((m).w & 0xFFFF0000u);

// ---- fused: values -> bf16 (one float4/thread) + histogram + rank ----
__global__ __launch_bounds__(256) void k_cvt_hist(const float4* __restrict__ v4,
                                                  const int* __restrict__ indices,
                                                  uint2* __restrict__ vb2,
                                                  int* __restrict__ hist,
                                                  unsigned char* __restrict__ rank) {
    const int p = blockIdx.x * 256 + threadIdx.x;
    const int idx = indices[p];
    const float4 a = v4[p];
    vb2[p] = make_uint2(pack_bf16x2(a.x, a.y), pack_bf16x2(a.z, a.w));
    rank[p] = (unsigned char)atomicAdd(&hist[idx], 1);
}

// ---- scan step a: per-block (1024-elem) sums ----
__global__ __launch_bounds__(256) void k2a_blocksum(const int* __restrict__ hist,
                                                    int* __restrict__ bsum) {
    __shared__ int red[256];
    const int t = threadIdx.x;
    const int base = blockIdx.x * 1024;
    int s = hist[base + t] + hist[base + t + 256] +
            hist[base + t + 512] + hist[base + t + 768];
    red[t] = s;
    __syncthreads();
    for (int off = 128; off > 0; off >>= 1) {
        if (t < off) red[t] += red[t + off];
        __syncthreads();
    }
    if (t == 0) bsum[blockIdx.x] = red[0];
}

// ---- scan step b+c fused ----
__global__ __launch_bounds__(256) void k2c_scan(const int* __restrict__ hist,
                                                const int* __restrict__ bsum,
                                                int* __restrict__ offs) {
    __shared__ int btmp[256];
    __shared__ int tmp[256];
    const int t = threadIdx.x;
    btmp[t] = bsum[t];
    __syncthreads();
    for (int off = 1; off < 256; off <<= 1) {  // inclusive scan of block sums
        int x = (t >= off) ? btmp[t - off] : 0;
        __syncthreads();
        btmp[t] += x;
        __syncthreads();
    }
    const int base_excl = btmp[blockIdx.x] - bsum[blockIdx.x];

    const int base = blockIdx.x * 1024 + t * 4;
    const int h0 = hist[base], h1 = hist[base + 1], h2 = hist[base + 2], h3 = hist[base + 3];
    const int tot = h0 + h1 + h2 + h3;
    tmp[t] = tot;
    __syncthreads();
    for (int off = 1; off < 256; off <<= 1) {
        int x = (t >= off) ? tmp[t - off] : 0;
        __syncthreads();
        tmp[t] += x;
        __syncthreads();
    }
    const int o0 = base_excl + (tmp[t] - tot);
    ((int4*)offs)[base >> 2] = make_int4(o0, o0 + h0, o0 + h0 + h1, o0 + h0 + h1 + h2);
}

// ---- bucket fill, atomic-free ----
__global__ __launch_bounds__(256) void k3_fill(const int* __restrict__ indices,
                                               const int* __restrict__ offs,
                                               const unsigned char* __restrict__ rank,
                                               unsigned short* __restrict__ sorted) {
    const int p = blockIdx.x * 256 + threadIdx.x;
    const int idx = indices[p];
    sorted[offs[idx] + (int)rank[p]] = (unsigned short)(p >> 5);
}

// ---- segmented reduce + fused debias (bf16 in, FP8 E4M3 out), 4-way MLP ----
__global__ __launch_bounds__(256) void k4_accum(const int* __restrict__ hist,
                                                const int* __restrict__ offs,
                                                const unsigned short* __restrict__ sorted,
                                                const uint4* __restrict__ vb,
                                                uint2* __restrict__ dbg) {
    const int t = threadIdx.x;
    const int sub = t >> 4;
    const int lane = t & 15;
    const int slot = blockIdx.x * 16 + sub;
    const int n = hist[slot];
    if (n == 0) return;  // untouched slot: never gathered
    const int off = offs[slot];
    float acc[8] = {0.f, 0.f, 0.f, 0.f, 0.f, 0.f, 0.f, 0.f};
    int j = 0;
    for (; j + 4 <= n; j += 4) {
        const int s0 = sorted[off + j + 0];
        const int s1 = sorted[off + j + 1];
        const int s2 = sorted[off + j + 2];
        const int s3 = sorted[off + j + 3];
        const uint4 m0 = vb[(size_t)s0 * 16 + lane];
        const uint4 m1 = vb[(size_t)s1 * 16 + lane];
        const uint4 m2 = vb[(size_t)s2 * 16 + lane];
        const uint4 m3 = vb[(size_t)s3 * 16 + lane];
        ACC8(acc, m0); ACC8(acc, m1); ACC8(acc, m2); ACC8(acc, m3);
    }
    for (; j < n; ++j) {
        const int src = sorted[off + j];
        const uint4 m = vb[(size_t)src * 16 + lane];
        ACC8(acc, m);
    }
    const float g = SCALE_F / ((float)n + EPS_F);
    int lo = __builtin_amdgcn_cvt_pk_fp8_f32(acc[0] * g, acc[1] * g, 0, false);
    lo     = __builtin_amdgcn_cvt_pk_fp8_f32(acc[2] * g, acc[3] * g, lo, true);
    int hi = __builtin_amdgcn_cvt_pk_fp8_f32(acc[4] * g, acc[5] * g, 0, false);
    hi     = __builtin_amdgcn_cvt_pk_fp8_f32(acc[6] * g, acc[7] * g, hi, true);
    dbg[(size_t)slot * 16 + lane] = make_uint2((unsigned)lo, (unsigned)hi);
}

// ---- gather: out[b] = mean over 32 pre-debiased fp8 rows ----
// 16 threads per key (8 row-lanes x 2 slot-halves), 16 keys/block.
__global__ __launch_bounds__(256) void k5_gather(const int* __restrict__ indices,
                                                 const uint4* __restrict__ dbg,
                                                 float* __restrict__ out) {
    __shared__ int sidx[16 * KH_SLOTS];
    const int t = threadIdx.x;
    const int* ibase = indices + (size_t)blockIdx.x * 16 * KH_SLOTS;
    sidx[t]       = ibase[t];
    sidx[t + 256] = ibase[t + 256];
    __syncthreads();

    const int sub  = t >> 4;        // key within block (0..15)
    const int lane = t & 7;         // uint4 index within the 128-B fp8 row
    const int half = (t >> 3) & 1;  // which 16 of the 32 slots
    const int b = blockIdx.x * 16 + sub;

    float acc[16];
    #pragma unroll
    for (int i = 0; i < 16; ++i) acc[i] = 0.f;

    const int* irow = sidx + sub * KH_SLOTS + half * 16;
    #pragma unroll
    for (int s = 0; s < 16; ++s) {
        const int idx = irow[s];
        const uint4 w = dbg[(size_t)idx * 8 + lane];
        const floatx2 p0 = __builtin_amdgcn_cvt_pk_f32_fp8((int)w.x, false);
        const floatx2 p1 = __builtin_amdgcn_cvt_pk_f32_fp8((int)w.x, true);
        const floatx2 p2 = __builtin_amdgcn_cvt_pk_f32_fp8((int)w.y, false);
        const floatx2 p3 = __builtin_amdgcn_cvt_pk_f32_fp8((int)w.y, true);
        const floatx2 p4 = __builtin_amdgcn_cvt_pk_f32_fp8((int)w.z, false);
        const floatx2 p5 = __builtin_amdgcn_cvt_pk_f32_fp8((int)w.z, true);
        const floatx2 p6 = __builtin_amdgcn_cvt_pk_f32_fp8((int)w.w, false);
        const floatx2 p7 = __builtin_amdgcn_cvt_pk_f32_fp8((int)w.w, true);
        acc[0]  += p0.x; acc[1]  += p0.y; acc[2]  += p1.x; acc[3]  += p1.y;
        acc[4]  += p2.x; acc[5]  += p2.y; acc[6]  += p3.x; acc[7]  += p3.y;
        acc[8]  += p4.x; acc[9]  += p4.y; acc[10] += p5.x; acc[11] += p5.y;
        acc[12] += p6.x; acc[13] += p6.y; acc[14] += p7.x; acc[15] += p7.y;
    }

    // merge the two slot-halves: partner differs only in bit 3 of tid
    #pragma unroll
    for (int i = 0; i < 16; ++i) acc[i] += __shfl_xor(acc[i], 8);

    const float inv = 1.0f / (float)KH_SLOTS;
    const int o = half * 8;  // half 0 writes floats 0..7, half 1 writes 8..15
    floatx4* orow = (floatx4*)(out + (size_t)b * D_FEAT + lane * 16);
    floatx4 w0 = {acc[o + 0] * inv, acc[o + 1] * inv, acc[o + 2] * inv, acc[o + 3] * inv};
    floatx4 w1 = {acc[o + 4] * inv, acc[o + 5] * inv, acc[o + 6] * inv, acc[o + 7] * inv};
    __builtin_nontemporal_store(w0, orow + half * 2 + 0);
    __builtin_nontemporal_store(w1, orow + half * 2 + 1);
}

extern "C" void kernel_launch(void* const* d_in, const int* in_sizes, int n_in,
                              void* d_out, int out_size, void* d_ws, size_t ws_size,
                              hipStream_t stream) {
    const int*   indices = (const int*)d_in[0];
    const float* values  = (const float*)d_in[1];
    float*       out     = (float*)d_out;

    // fixed ws region (as before): hist[D] offs[D] bsum[256] sorted[NPAIR]
    int* wsi    = (int*)d_ws;
    int* hist   = wsi;
    int* offs   = wsi + D_SLOTS;
    int* bsum   = wsi + 2 * D_SLOTS;
    unsigned short* sorted = (unsigned short*)(wsi + 2 * D_SLOTS + 256);

    const size_t fixed_b   = (size_t)(2 * D_SLOTS + 256) * 4 + (size_t)NPAIR * 2;  // 4,195,328
    const size_t dbg_b     = (size_t)D_SLOTS * 128;                                 // 33,554,432
    const size_t vb_b      = (size_t)B_KEYS * 256;                                  //  8,388,608
    const size_t rank_b    = (size_t)NPAIR;                                         //  1,048,576
    const size_t fixed_al  = (fixed_b + 255) & ~(size_t)255;

    uint2*         dbg;
    unsigned*      vb;
    unsigned char* rank;
    if (ws_size >= fixed_al + dbg_b + vb_b + rank_b) {
        // scratch fully in d_ws: d_in[2] is never written -> no re-poison needed
        unsigned char* s = (unsigned char*)d_ws + fixed_al;
        dbg  = (uint2*)s;
        vb   = (unsigned*)(s + dbg_b);
        rank = s + dbg_b + vb_b;
    } else {
        // fallback: exact R12 layout inside d_in[2] ("memory", 134 MB)
        unsigned* mem_u = (unsigned*)d_in[2];
        dbg  = (uint2*)mem_u;
        vb   = mem_u + (size_t)D_SLOTS * 32;
        rank = (unsigned char*)(mem_u + (size_t)D_SLOTS * 32 + (size_t)B_KEYS * 64);
    }

    (void)hipMemsetAsync(hist, 0, (size_t)D_SLOTS * sizeof(int), stream);
    k_cvt_hist  <<<NPAIR / 256, 256, 0, stream>>>((const float4*)values, indices,
                                                  (uint2*)vb, hist, rank);
    k2a_blocksum<<<256, 256, 0, stream>>>(hist, bsum);
    k2c_scan    <<<256, 256, 0, stream>>>(hist, bsum, offs);
    k3_fill     <<<NPAIR / 256, 256, 0, stream>>>(indices, offs, rank, sorted);
    k4_accum    <<<D_SLOTS / 16, 256, 0, stream>>>(hist, offs, sorted, (const uint4*)vb, dbg);
    k5_gather   <<<B_KEYS / 16, 256, 0, stream>>>(indices, (const uint4*)dbg, out);
}

// Round 8
// 283.900 us; speedup vs baseline: 1.2692x; 1.0435x over previous
//
#include <hip/hip_runtime.h>

// Problem constants (from reference):
//   D = 262144 slots, d = 128, KH = 32 slots/key, B = 32768 keys
#define D_SLOTS   262144
#define D_FEAT    128
#define KH_SLOTS  32
#define B_KEYS    32768
#define NPAIR     (B_KEYS * KH_SLOTS)      // 1,048,576 (b,slot) pairs
#define SCALE_F   0.17677669529663687f     // 1/sqrt(32)
#define EPS_F     1e-8f

// Strategy (R18): LINKED-LIST redesign. R17 (scratch->ws) was null; the
// ~160us unaccounted (295 total - 135 probed work) must be some mix of
// {sort3 real cost incl. k3's 1M random ushort RMW scatter, ~20us/node
// dispatch overhead x7}. This round deletes both candidates at once:
//   k1: next[p] = atomicExch(&head[idx], p)  (same atomic class as before)
//   k4: walks per-slot chain (avg depth 4), counting n while accumulating
//   k2a/k2c/k3 DELETED. 7 nodes -> 4 nodes.
// Pre-committed: <=240 -> consolidation pays, go cooperative mega-kernel
// next; >=285 -> remainder intrinsic to k1/k4/k5, re-probe new structure.
//
// ws layout (if ws_size >= ~47.2 MB; else dbg/vb fall back to d_in[2]):
//   head int[D]        per-slot chain head, -1 = empty (1 MB)
//   next int[NPAIR]    chain successor per pair (4 MB)
//   dbg  uint2[D*16]   debiased fp8 rows, 128 B/row (33.5 MB)
//   vb   uint[B*64]    values as bf16 (8.4 MB)

typedef float floatx2 __attribute__((ext_vector_type(2)));
typedef float floatx4 __attribute__((ext_vector_type(4)));

__device__ __forceinline__ unsigned pack_bf16x2(float a, float b) {
    unsigned ua = __float_as_uint(a), ub = __float_as_uint(b);
    ua = (ua + 0x7FFFu + ((ua >> 16) & 1u)) >> 16;
    ub = (ub + 0x7FFFu + ((ub >> 16) & 1u)) >> 16;
    return ua | (ub << 16);
}

#define ACC8(acc, m)                                   \
    acc[0] += __uint_as_float((m).x << 16);            \
    acc[1] += __uint_as_float((m).x & 0xFFFF0000u);    \
    acc[2] += __uint_as_float((m).y << 16);            \
    acc[3] += __uint_as_float((m).y & 0xFFFF0000u);    \
    acc[4] += __uint_as_float((m).z << 16);            \
    acc[5] += __uint_as_float((m).z & 0xFFFF0000u);    \
    acc[6] += __uint_as_float((m).w << 16);            \
    acc[7] += __uint_as_float((m).w & 0xFFFF0000u);

// ---- fused: values -> bf16 + linked-list push (replaces hist+rank+sort) ----
__global__ __launch_bounds__(256) void k1_cvt_link(const float4* __restrict__ v4,
                                                   const int* __restrict__ indices,
                                                   uint2* __restrict__ vb2,
                                                   int* __restrict__ head,
                                                   int* __restrict__ next) {
    const int p = blockIdx.x * 256 + threadIdx.x;
    const int idx = indices[p];
    const float4 a = v4[p];
    vb2[p] = make_uint2(pack_bf16x2(a.x, a.y), pack_bf16x2(a.z, a.w));
    next[p] = atomicExch(&head[idx], p);
}

// ---- segmented reduce via chain walk + fused debias (bf16 in, FP8 out) ----
// 16 lanes per slot row (uint4 = 8 bf16 each), 16 slots per block.
// next[p] is the same address across the 16 lanes -> broadcast load, and it
// issues in parallel with the vb row gather for the current p.
__global__ __launch_bounds__(256) void k4_accum(const int* __restrict__ head,
                                                const int* __restrict__ next,
                                                const uint4* __restrict__ vb,
                                                uint2* __restrict__ dbg) {
    const int t = threadIdx.x;
    const int sub = t >> 4;
    const int lane = t & 15;
    const int slot = blockIdx.x * 16 + sub;
    int p = head[slot];
    if (p < 0) return;  // untouched slot: never gathered
    float acc[8] = {0.f, 0.f, 0.f, 0.f, 0.f, 0.f, 0.f, 0.f};
    int n = 0;
    while (p >= 0) {
        const uint4 m = vb[(size_t)(p >> 5) * 16 + lane];
        const int pn = next[p];
        ACC8(acc, m);
        ++n;
        p = pn;
    }
    const float g = SCALE_F / ((float)n + EPS_F);
    int lo = __builtin_amdgcn_cvt_pk_fp8_f32(acc[0] * g, acc[1] * g, 0, false);
    lo     = __builtin_amdgcn_cvt_pk_fp8_f32(acc[2] * g, acc[3] * g, lo, true);
    int hi = __builtin_amdgcn_cvt_pk_fp8_f32(acc[4] * g, acc[5] * g, 0, false);
    hi     = __builtin_amdgcn_cvt_pk_fp8_f32(acc[6] * g, acc[7] * g, hi, true);
    dbg[(size_t)slot * 16 + lane] = make_uint2((unsigned)lo, (unsigned)hi);
}

// ---- gather: out[b] = mean over 32 pre-debiased fp8 rows ----
// 16 threads per key (8 row-lanes x 2 slot-halves), 16 keys/block.
__global__ __launch_bounds__(256) void k5_gather(const int* __restrict__ indices,
                                                 const uint4* __restrict__ dbg,
                                                 float* __restrict__ out) {
    __shared__ int sidx[16 * KH_SLOTS];
    const int t = threadIdx.x;
    const int* ibase = indices + (size_t)blockIdx.x * 16 * KH_SLOTS;
    sidx[t]       = ibase[t];
    sidx[t + 256] = ibase[t + 256];
    __syncthreads();

    const int sub  = t >> 4;        // key within block (0..15)
    const int lane = t & 7;         // uint4 index within the 128-B fp8 row
    const int half = (t >> 3) & 1;  // which 16 of the 32 slots
    const int b = blockIdx.x * 16 + sub;

    float acc[16];
    #pragma unroll
    for (int i = 0; i < 16; ++i) acc[i] = 0.f;

    const int* irow = sidx + sub * KH_SLOTS + half * 16;
    #pragma unroll
    for (int s = 0; s < 16; ++s) {
        const int idx = irow[s];
        const uint4 w = dbg[(size_t)idx * 8 + lane];
        const floatx2 p0 = __builtin_amdgcn_cvt_pk_f32_fp8((int)w.x, false);
        const floatx2 p1 = __builtin_amdgcn_cvt_pk_f32_fp8((int)w.x, true);
        const floatx2 p2 = __builtin_amdgcn_cvt_pk_f32_fp8((int)w.y, false);
        const floatx2 p3 = __builtin_amdgcn_cvt_pk_f32_fp8((int)w.y, true);
        const floatx2 p4 = __builtin_amdgcn_cvt_pk_f32_fp8((int)w.z, false);
        const floatx2 p5 = __builtin_amdgcn_cvt_pk_f32_fp8((int)w.z, true);
        const floatx2 p6 = __builtin_amdgcn_cvt_pk_f32_fp8((int)w.w, false);
        const floatx2 p7 = __builtin_amdgcn_cvt_pk_f32_fp8((int)w.w, true);
        acc[0]  += p0.x; acc[1]  += p0.y; acc[2]  += p1.x; acc[3]  += p1.y;
        acc[4]  += p2.x; acc[5]  += p2.y; acc[6]  += p3.x; acc[7]  += p3.y;
        acc[8]  += p4.x; acc[9]  += p4.y; acc[10] += p5.x; acc[11] += p5.y;
        acc[12] += p6.x; acc[13] += p6.y; acc[14] += p7.x; acc[15] += p7.y;
    }

    // merge the two slot-halves: partner differs only in bit 3 of tid
    #pragma unroll
    for (int i = 0; i < 16; ++i) acc[i] += __shfl_xor(acc[i], 8);

    const float inv = 1.0f / (float)KH_SLOTS;
    const int o = half * 8;  // half 0 writes floats 0..7, half 1 writes 8..15
    floatx4* orow = (floatx4*)(out + (size_t)b * D_FEAT + lane * 16);
    floatx4 w0 = {acc[o + 0] * inv, acc[o + 1] * inv, acc[o + 2] * inv, acc[o + 3] * inv};
    floatx4 w1 = {acc[o + 4] * inv, acc[o + 5] * inv, acc[o + 6] * inv, acc[o + 7] * inv};
    __builtin_nontemporal_store(w0, orow + half * 2 + 0);
    __builtin_nontemporal_store(w1, orow + half * 2 + 1);
}

extern "C" void kernel_launch(void* const* d_in, const int* in_sizes, int n_in,
                              void* d_out, int out_size, void* d_ws, size_t ws_size,
                              hipStream_t stream) {
    const int*   indices = (const int*)d_in[0];
    const float* values  = (const float*)d_in[1];
    float*       out     = (float*)d_out;

    // fixed ws region: head[D] next[NPAIR]
    int* head = (int*)d_ws;
    int* next = head + D_SLOTS;

    const size_t fixed_b  = (size_t)(D_SLOTS + NPAIR) * 4;   // 5,242,880
    const size_t dbg_b    = (size_t)D_SLOTS * 128;           // 33,554,432
    const size_t vb_b     = (size_t)B_KEYS * 256;            //  8,388,608
    const size_t fixed_al = (fixed_b + 255) & ~(size_t)255;

    uint2*    dbg;
    unsigned* vb;
    if (ws_size >= fixed_al + dbg_b + vb_b) {
        unsigned char* s = (unsigned char*)d_ws + fixed_al;
        dbg = (uint2*)s;
        vb  = (unsigned*)(s + dbg_b);
    } else {
        // fallback: scratch inside d_in[2] ("memory", 134 MB, restored by harness)
        unsigned* mem_u = (unsigned*)d_in[2];
        dbg = (uint2*)mem_u;
        vb  = mem_u + (size_t)D_SLOTS * 32;
    }

    // head = -1 everywhere (0xFF byte fill)
    (void)hipMemsetAsync(head, 0xFF, (size_t)D_SLOTS * sizeof(int), stream);
    k1_cvt_link<<<NPAIR / 256, 256, 0, stream>>>((const float4*)values, indices,
                                                 (uint2*)vb, head, next);
    k4_accum   <<<D_SLOTS / 16, 256, 0, stream>>>(head, next, (const uint4*)vb, dbg);
    k5_gather  <<<B_KEYS / 16, 256, 0, stream>>>(indices, (const uint4*)dbg, out);
}